// Round 2
// baseline (1822.357 us; speedup 1.0000x reference)
//
#include <hip/hip_runtime.h>

typedef unsigned int u32;
typedef unsigned short u16;
typedef _Float16 f16;
typedef f16 f16x8 __attribute__((ext_vector_type(8)));
typedef float f32x4 __attribute__((ext_vector_type(4)));
typedef u16 u16x8 __attribute__((ext_vector_type(8)));

#define DIM 1024
#define BATCH 32768
#define RANK 32
#define NLIN 18

__device__ __forceinline__ u16 f2h(float f) {
    f16 h = (f16)f;
    return *(u16*)&h;
}
__device__ __forceinline__ float h2f(u16 u) {
    f16 h;
    *(u16*)&h = u;
    return (float)h;
}

__device__ __forceinline__ void gload16(const u16* g, u16* l) {
    __builtin_amdgcn_global_load_lds((__attribute__((address_space(1))) const void*)g,
                                     (__attribute__((address_space(3))) void*)l,
                                     16, 0, 0);
}

// ---- W_eff = dequant(wq, scales) + lb @ la  -> fp16 [NLIN][DIM][DIM] ----
__global__ __launch_bounds__(256) void build_weff(
    const int* __restrict__ wq, const float* __restrict__ scales,
    const float* __restrict__ la, const float* __restrict__ lb,
    u16* __restrict__ weff)
{
    int rb = blockIdx.x;   // 0..63, 16 rows each
    int li = blockIdx.y;   // 0..17
    int tid = threadIdx.x;
    int row0 = rb * 16;
    __shared__ float lb_s[16][RANK];
    __shared__ float la_s[RANK][256];
    for (int idx = tid; idx < 16 * RANK; idx += 256) {
        int o = idx >> 5, r = idx & 31;
        lb_s[o][r] = lb[((size_t)li * DIM + row0 + o) * RANK + r];
    }
    const int* wqL = wq + (size_t)li * DIM * DIM;
    const float* sL = scales + (size_t)li * (DIM * DIM / 16);
    u16* wout = weff + (size_t)li * DIM * DIM;
    for (int kc = 0; kc < DIM; kc += 256) {
        __syncthreads();
        #pragma unroll
        for (int j = 0; j < 32; ++j) {
            int idx = j * 256 + tid;
            int r = idx >> 8, c = idx & 255;
            la_s[r][c] = la[((size_t)li * RANK + r) * DIM + kc + c];
        }
        __syncthreads();
        int k = kc + tid;
        for (int o = 0; o < 16; ++o) {
            int og = row0 + o;
            float acc = ((float)wqL[og * DIM + k] - 8.0f) * sL[(og << 6) + (k >> 4)];
            #pragma unroll
            for (int r = 0; r < RANK; ++r)
                acc += lb_s[o][r] * la_s[r][tid];
            wout[og * DIM + k] = f2h(acc);
        }
    }
}

// ---- x fp32 -> fp16 ----
__global__ __launch_bounds__(256) void xcast(const float* __restrict__ x, u16* __restrict__ o) {
    size_t i = ((size_t)blockIdx.x * 256 + threadIdx.x) * 8;
    float4 a = *(const float4*)(x + i);
    float4 b = *(const float4*)(x + i + 4);
    u16x8 v;
    v[0] = f2h(a.x); v[1] = f2h(a.y); v[2] = f2h(a.z); v[3] = f2h(a.w);
    v[4] = f2h(b.x); v[5] = f2h(b.y); v[6] = f2h(b.z); v[7] = f2h(b.w);
    *(u16x8*)(o + i) = v;
}

// ---- GEMM: out[m,n] = sum_k X[m,k] * W[n,k] + bias[n] (+res) (+relu) ----
// 128x128 tile, BK=64, 4 waves (2x2), each wave 64x64 via 4x4 frags of 16x16x32.
// LDS staged by global_load_lds w=16; st-style XOR swizzle: chunk ^= (row&7),
// applied on the GLOBAL source address (LDS dest stays linear) and on the
// ds_read address — both-sides-or-neither (rule #21).
// EPI: 0 = relu(acc+bias) -> fp16 ; 1 = acc+bias+res -> fp16 ; 2 = acc+bias+res -> fp32
template<int EPI>
__global__ __launch_bounds__(256) void gemm_k(
    const u16* __restrict__ X, const u16* __restrict__ W,
    const float* __restrict__ bias, const u16* __restrict__ res,
    void* __restrict__ outp)
{
    __shared__ __align__(16) u16 As[128 * 64];
    __shared__ __align__(16) u16 Bs[128 * 64];
    int tid = threadIdx.x;
    int bid = blockIdx.x;
    // XCD-bijective swizzle (2048 % 8 == 0)
    int wg = (bid & 7) * 256 + (bid >> 3);
    int bm = wg >> 3;          // 0..255
    int bn = wg & 7;           // 0..7
    int wv = tid >> 6;
    int lane = tid & 63;
    int wm = wv >> 1, wn = wv & 1;

    size_t gA[4], gB[4];
    int ldsOff[4];
    #pragma unroll
    for (int i = 0; i < 4; ++i) {
        int c = i * 256 + tid;          // chunk 0..511 (16B each)
        int row = c >> 3;               // 0..127
        int lc = (c & 7) ^ (row & 7);   // logical chunk this slot holds
        gA[i] = ((size_t)(bm * 128 + row)) * DIM + lc * 8;
        gB[i] = ((size_t)(bn * 128 + row)) * DIM + lc * 8;
        ldsOff[i] = c * 8;              // u16 elements (16B chunks)
    }

    f32x4 acc[4][4];
    #pragma unroll
    for (int i = 0; i < 4; ++i)
        #pragma unroll
        for (int j = 0; j < 4; ++j)
            acc[i][j] = (f32x4){0.f, 0.f, 0.f, 0.f};

    int rA = wm * 64 + (lane & 15);
    int rB = wn * 64 + (lane & 15);
    int kg = lane >> 4;   // 0..3

    for (int kt = 0; kt < 16; ++kt) {
        int k0 = kt * 64;
        #pragma unroll
        for (int i = 0; i < 4; ++i) gload16(X + gA[i] + k0, &As[ldsOff[i]]);
        #pragma unroll
        for (int i = 0; i < 4; ++i) gload16(W + gB[i] + k0, &Bs[ldsOff[i]]);
        __syncthreads();
        #pragma unroll
        for (int ks = 0; ks < 2; ++ks) {
            f16x8 a[4], b[4];
            #pragma unroll
            for (int f = 0; f < 4; ++f) {
                int r = rA + f * 16;
                int ch = (ks * 4 + kg) ^ (r & 7);
                a[f] = *(const f16x8*)((const char*)As + r * 128 + ch * 16);
                int r2 = rB + f * 16;
                int ch2 = (ks * 4 + kg) ^ (r2 & 7);
                b[f] = *(const f16x8*)((const char*)Bs + r2 * 128 + ch2 * 16);
            }
            #pragma unroll
            for (int fm = 0; fm < 4; ++fm)
                #pragma unroll
                for (int fn = 0; fn < 4; ++fn)
                    acc[fm][fn] = __builtin_amdgcn_mfma_f32_16x16x32_f16(
                        a[fm], b[fn], acc[fm][fn], 0, 0, 0);
        }
        __syncthreads();
    }

    // epilogue: C/D layout col=lane&15, row=(lane>>4)*4+reg
    int mb = bm * 128 + wm * 64 + (lane >> 4) * 4;
    int nb = bn * 128 + wn * 64 + (lane & 15);
    float bv[4];
    #pragma unroll
    for (int fn = 0; fn < 4; ++fn) bv[fn] = bias[nb + fn * 16];
    #pragma unroll
    for (int fm = 0; fm < 4; ++fm) {
        #pragma unroll
        for (int reg = 0; reg < 4; ++reg) {
            int m = mb + fm * 16 + reg;
            #pragma unroll
            for (int fn = 0; fn < 4; ++fn) {
                int n = nb + fn * 16;
                float v = acc[fm][fn][reg] + bv[fn];
                if (EPI == 0) {
                    v = fmaxf(v, 0.0f);
                    ((u16*)outp)[(size_t)m * DIM + n] = f2h(v);
                } else {
                    v += h2f(res[(size_t)m * DIM + n]);
                    if (EPI == 1) ((u16*)outp)[(size_t)m * DIM + n] = f2h(v);
                    else          ((float*)outp)[(size_t)m * DIM + n] = v;
                }
            }
        }
    }
}

// ---- LayerNorm: fp16 in -> fp16 out, one wave per row ----
__global__ __launch_bounds__(256) void ln_k(const u16* __restrict__ in,
    const float* __restrict__ g, const float* __restrict__ b, u16* __restrict__ out)
{
    int row = blockIdx.x * 4 + (threadIdx.x >> 6);
    int lane = threadIdx.x & 63;
    const u16* rp = in + (size_t)row * DIM;
    u16x8 v0 = *(const u16x8*)(rp + lane * 8);
    u16x8 v1 = *(const u16x8*)(rp + 512 + lane * 8);
    float f[16];
    #pragma unroll
    for (int j = 0; j < 8; ++j) { f[j] = h2f(v0[j]); f[8 + j] = h2f(v1[j]); }
    float s = 0.f, sq = 0.f;
    #pragma unroll
    for (int j = 0; j < 16; ++j) { s += f[j]; sq += f[j] * f[j]; }
    #pragma unroll
    for (int m = 1; m < 64; m <<= 1) { s += __shfl_xor(s, m); sq += __shfl_xor(sq, m); }
    float mean = s * (1.0f / 1024.0f);
    float var = sq * (1.0f / 1024.0f) - mean * mean;
    float rstd = 1.0f / sqrtf(var + 1e-5f);
    u16x8 o0, o1;
    #pragma unroll
    for (int j = 0; j < 8; ++j) {
        int c0 = lane * 8 + j, c1 = 512 + lane * 8 + j;
        o0[j] = f2h((f[j] - mean) * rstd * g[c0] + b[c0]);
        o1[j] = f2h((f[8 + j] - mean) * rstd * g[c1] + b[c1]);
    }
    u16* op = out + (size_t)row * DIM;
    *(u16x8*)(op + lane * 8) = o0;
    *(u16x8*)(op + 512 + lane * 8) = o1;
}

extern "C" void kernel_launch(void* const* d_in, const int* in_sizes, int n_in,
                              void* d_out, int out_size, void* d_ws, size_t ws_size,
                              hipStream_t stream) {
    const float* x      = (const float*)d_in[0];
    const int*   wq     = (const int*)d_in[1];
    const float* scales = (const float*)d_in[2];
    const float* bias   = (const float*)d_in[3];
    const float* la     = (const float*)d_in[4];
    const float* lb     = (const float*)d_in[5];
    const float* gamma  = (const float*)d_in[6];
    const float* beta   = (const float*)d_in[7];

    char* ws = (char*)d_ws;
    u16* Weff = (u16*)ws;                                      // 37,748,736 B
    u16* actA = (u16*)(ws + (size_t)NLIN * DIM * DIM * 2);     // 67,108,864 B
    u16* actB = actA + (size_t)BATCH * DIM;                    // 67,108,864 B
    u16* dob  = (u16*)d_out;   // d_out doubles as fp16 scratch (134 MB total)
    float* dof = (float*)d_out;

    build_weff<<<dim3(64, 18), 256, 0, stream>>>(wq, scales, la, lb, Weff);
    xcast<<<(BATCH * DIM) / 2048, 256, 0, stream>>>(x, actA);

    int li = 0;
    for (int blk = 0; blk < 6; ++blk) {
        const u16* w0 = Weff + (size_t)(li + 0) * DIM * DIM;
        const u16* w1 = Weff + (size_t)(li + 1) * DIM * DIM;
        const u16* w2 = Weff + (size_t)(li + 2) * DIM * DIM;
        const float* b0 = bias + (li + 0) * DIM;
        const float* b1 = bias + (li + 1) * DIM;
        const float* b2 = bias + (li + 2) * DIM;
        if (blk < 5) {
            // X(actA) -> h1(actB) -> h2(d_out fp16) -> h3(actB) -> LN -> actA
            gemm_k<0><<<2048, 256, 0, stream>>>(actA, w0, b0, nullptr, actB);
            gemm_k<0><<<2048, 256, 0, stream>>>(actB, w1, b1, nullptr, dob);
            gemm_k<1><<<2048, 256, 0, stream>>>(dob,  w2, b2, actA, actB);
            ln_k<<<BATCH / 4, 256, 0, stream>>>(actB, gamma + blk * DIM, beta + blk * DIM, actA);
        } else {
            // final block: keep d_out free of live reads at the fp32 write
            gemm_k<0><<<2048, 256, 0, stream>>>(actA, w0, b0, nullptr, dob);
            gemm_k<0><<<2048, 256, 0, stream>>>(dob,  w1, b1, nullptr, actB);
            gemm_k<2><<<2048, 256, 0, stream>>>(actB, w2, b2, actA, (void*)dof);
        }
        li += 3;
    }
}